// Round 6
// baseline (231.604 us; speedup 1.0000x reference)
//
#include <hip/hip_runtime.h>
#include <math.h>

// KAN attention: two spline-edge reductions (q,k branches) + bias + softmax(dim=8).
// batch=8, act_in=act_out=2048, C=8 coeffs/edge, N=4.19M edges/branch.
// HBM floor ~340 MB -> ~54 us at 6.3 TB/s achievable.
//
// R5 -> R6: the allocator refuses to go above 64 VGPRs for this kernel
// (launch_bounds and waves_per_eu both ignored; 104 MB scratch spill both
// rounds). Stop fighting it: shrink the step's live set to fit 64. Each wave
// now does 1 o per step (16 steps) -> 4 float4 coef + acc[8] + transients
// ~ 55 VGPRs, zero spill. Reduction cheapened: 3-level butterfly (octet sums
// of all 8 b) -> cndmask-select b=l&7 -> 3-level butterfly on one value
// (27 shuffles vs 48). Structure otherwise identical to R4/R5.

#define ACT 2048
#define BATCH 8
#define IBLK 64               // i per block (= lanes of one wave)
#define NIC (ACT / IBLK)      // 32 i-chunks
#define OBLK 64               // o per block
#define NOC (ACT / OBLK)      // 32 o-chunks

__device__ __forceinline__ float dot4(const float4& a, const float4& b) {
  float r = a.x * b.x;
  r = fmaf(a.y, b.y, r);
  r = fmaf(a.z, b.z, r);
  r = fmaf(a.w, b.w, r);
  return r;
}

// ---------------------------------------------------------------------------
// Kernel 1: B-spline basis (Cox-de Boor, k=3, 12 uniform knots at -2.2+0.4j)
// and silu(x) for all (b,i) of both branches.
// Layout: B[ic][b*2+h][il] as float4 (ic=i/64, il=i%64), base[ic][b][il].
// ---------------------------------------------------------------------------
__global__ void kan_precompute(const float* __restrict__ q, const float* __restrict__ k,
                               float4* __restrict__ Bq, float4* __restrict__ Bk,
                               float* __restrict__ baseq, float* __restrict__ basek) {
  int tid = blockIdx.x * blockDim.x + threadIdx.x;
  if (tid >= ACT * BATCH) return;
  int il = tid & (IBLK - 1);
  int b = (tid >> 6) & 7;
  int ic = tid >> 9;
  int i = ic * IBLK + il;
  const float t0 = -2.2f;
  const float h = 0.4f;
  for (int br = 0; br < 2; ++br) {
    const float* xsrc = br ? k : q;
    float4* Bdst = br ? Bk : Bq;
    float* basedst = br ? basek : baseq;
    float x = xsrc[(size_t)b * ACT + i];
    float Bv[11];
#pragma unroll
    for (int j = 0; j < 11; ++j) {
      float tj = t0 + h * (float)j;
      float tj1 = t0 + h * (float)(j + 1);
      Bv[j] = (x >= tj && x < tj1) ? 1.0f : 0.0f;
    }
#pragma unroll
    for (int d = 1; d <= 3; ++d) {
      float inv = 1.0f / (h * (float)d);
#pragma unroll
      for (int j = 0; j + d < 11; ++j) {
        float tj = t0 + h * (float)j;
        float tjd1 = t0 + h * (float)(j + d + 1);
        Bv[j] = (x - tj) * inv * Bv[j] + (tjd1 - x) * inv * Bv[j + 1];
      }
    }
    Bdst[((size_t)ic * 16 + b * 2 + 0) * IBLK + il] = make_float4(Bv[0], Bv[1], Bv[2], Bv[3]);
    Bdst[((size_t)ic * 16 + b * 2 + 1) * IBLK + il] = make_float4(Bv[4], Bv[5], Bv[6], Bv[7]);
    basedst[((size_t)ic * 8 + b) * IBLK + il] = x / (1.0f + expf(-x));
  }
}

// ---------------------------------------------------------------------------
// Kernel 2: main reduction. 1024 blocks x 256 threads, all resident (4/CU,
// LDS 36 KB). Block = (ic: 64 i) x (oc: 64 o). Wave w (lane l = i) handles
// one o per step, 16 steps, NO barriers in the loop. Per step: 8 VMEM loads
// (coef q/k + 4 scalars), b-loop reuses LDS B rows across both branches,
// cheap two-stage butterfly reduce, plain stores to y_part[o][ic][b].
// Live set ~55 VGPRs -> fits the 64-VGPR budget with no spill (R4/R5 lesson).
// ---------------------------------------------------------------------------
__global__ __launch_bounds__(256, 4) void kan_main(
    const float* __restrict__ coef_q, const float* __restrict__ coef_k,
    const float* __restrict__ scale_base, const float* __restrict__ scale_sp,
    const float* __restrict__ mask_q, const float* __restrict__ mask_k,
    const float4* __restrict__ Bq, const float4* __restrict__ Bk,
    const float* __restrict__ baseq, const float* __restrict__ basek,
    float* __restrict__ y_part) {
  __shared__ float4 BsQ[16 * IBLK];   // [(b*2+h)*64 + il]
  __shared__ float4 BsK[16 * IBLK];
  __shared__ float basQ[8 * IBLK];    // [b*64 + il]
  __shared__ float basK[8 * IBLK];

  const int t = threadIdx.x;
  const int l = t & 63;               // lane = i within chunk
  const int w = t >> 6;               // wave index (0..3)
  const int oc = blockIdx.x >> 5;
  const int ic = blockIdx.x & 31;
  const int o0 = oc * OBLK;
  const size_t ibase = (size_t)ic * IBLK + l;

  // ---- stage B/base for both branches (once per block lifetime) ----
  {
    const float4* srcq = Bq + (size_t)ic * 16 * IBLK;
    const float4* srck = Bk + (size_t)ic * 16 * IBLK;
#pragma unroll
    for (int r = 0; r < 4; ++r) {
      BsQ[r * 256 + t] = srcq[r * 256 + t];
      BsK[r * 256 + t] = srck[r * 256 + t];
    }
    if (t < 128) {
      reinterpret_cast<float4*>(basQ)[t] =
          reinterpret_cast<const float4*>(baseq + (size_t)ic * 8 * IBLK)[t];
    } else {
      reinterpret_cast<float4*>(basK)[t - 128] =
          reinterpret_cast<const float4*>(basek + (size_t)ic * 8 * IBLK)[t - 128];
    }
  }
  __syncthreads();

#pragma unroll 1
  for (int s = 0; s < 16; ++s) {
    const int oa = o0 + s * 4 + w;
    const size_t e = (size_t)oa * ACT + ibase;

    // 2 x dwordx4 per branch (lane-stride 32 B, coalesced) + 4 scalars.
    const float4* cpq = reinterpret_cast<const float4*>(coef_q + e * 8);
    const float4* cpk = reinterpret_cast<const float4*>(coef_k + e * 8);
    float4 cq0 = cpq[0], cq1 = cpq[1];
    float4 ck0 = cpk[0], ck1 = cpk[1];
    float mq = mask_q[e], mk = mask_k[e];
    float sb = scale_base[e], ss = scale_sp[e];

    float vbq = mq * sb, vsq = mq * ss, vbk = mk * sb, vsk = mk * ss;

    float acc[BATCH];
#pragma unroll
    for (int b = 0; b < BATCH; ++b) {
      const float4 Bq0 = BsQ[(b * 2 + 0) * IBLK + l];
      const float4 Bq1 = BsQ[(b * 2 + 1) * IBLK + l];
      const float4 Bk0 = BsK[(b * 2 + 0) * IBLK + l];
      const float4 Bk1 = BsK[(b * 2 + 1) * IBLK + l];
      const float bsq = basQ[b * IBLK + l];
      const float bsk = basK[b * IBLK + l];

      float dq = dot4(Bq0, cq0) + dot4(Bq1, cq1);
      float dk = dot4(Bk0, ck0) + dot4(Bk1, ck1);
      float a = vsq * dq;
      a = fmaf(vsk, dk, a);
      a = fmaf(vbq, bsq, a);
      a = fmaf(vbk, bsk, a);
      acc[b] = a;
    }

    // Stage 1: 3-level butterfly over low lane bits -> every lane holds its
    // octet's sum for all 8 b.
#pragma unroll
    for (int b = 0; b < BATCH; ++b) {
#pragma unroll
      for (int off = 1; off < 8; off <<= 1) acc[b] += __shfl_xor(acc[b], off);
    }
    // Stage 2: select b = l&7 (compile-time-indexed cndmask chain), then
    // 3 more levels across octets -> total sum for b=l&7 in every lane.
    float v = acc[0];
#pragma unroll
    for (int b = 1; b < BATCH; ++b) v = ((l & 7) == b) ? acc[b] : v;
#pragma unroll
    for (int off = 8; off < 64; off <<= 1) v += __shfl_xor(v, off);

    if (l < 8) y_part[(size_t)oa * (NIC * 8) + ic * 8 + l] = v;
  }
}

// ---------------------------------------------------------------------------
// Kernel 3: sum 32 i-chunk partials per (o,b), add bias, softmax over groups
// of 8 outputs. One wave per output row (b,grp); 4 rows per 256-thread block.
// Lane l: op = l>>3 (8 o's), sub = l&7 (partial-chunk slice).
// ---------------------------------------------------------------------------
__global__ void kan_softmax(const float* __restrict__ y_part,
                            const float* __restrict__ bias,
                            float* __restrict__ out) {
  const int t = threadIdx.x;
  const int wid = blockIdx.x * 4 + (t >> 6);   // row id, 0..2047
  const int b = wid >> 8;
  const int grp = wid & 255;
  const int l = t & 63;
  const int op = l >> 3;                       // o within group
  const int sub = l & 7;
  const int o = grp * 8 + op;

  float p = 0.0f;
#pragma unroll
  for (int j = 0; j < 4; ++j) {
    int icc = sub + 8 * j;
    p += y_part[(size_t)o * (NIC * 8) + icc * 8 + b];
  }
  // sum the 8 sub-partials within each o-group (lanes 8*op .. 8*op+7)
#pragma unroll
  for (int off = 1; off < 8; off <<= 1) p += __shfl_xor(p, off);
  float v = p + bias[o];
  // softmax across the 8 o-groups (xor offs 8,16,32 span the groups)
  float m = v;
#pragma unroll
  for (int off = 8; off < 64; off <<= 1) m = fmaxf(m, __shfl_xor(m, off));
  float e = expf(v - m);
  float ssum = e;
#pragma unroll
  for (int off = 8; off < 64; off <<= 1) ssum += __shfl_xor(ssum, off);
  if (sub == 0) out[(size_t)b * ACT + o] = e / ssum;
}

// ---------------------------------------------------------------------------
// Workspace layout (floats):
//   y_part @ 0      : 524288  ([o][ic][b], fully rewritten each call)
//   Bq     @ 524288 : 131072  ([ic][b*2+h][il] float4)
//   Bk     @ 655360 : 131072
//   baseq  @ 786432 : 16384   ([ic][b][il])
//   basek  @ 802816 : 16384
// total 819200 floats = 3.125 MiB. No init needed (every slot written).
// ---------------------------------------------------------------------------
extern "C" void kernel_launch(void* const* d_in, const int* in_sizes, int n_in,
                              void* d_out, int out_size, void* d_ws, size_t ws_size,
                              hipStream_t stream) {
  const float* q          = (const float*)d_in[0];
  const float* k          = (const float*)d_in[1];
  const float* coef_q     = (const float*)d_in[2];
  const float* coef_k     = (const float*)d_in[3];
  const float* scale_base = (const float*)d_in[4];
  const float* scale_sp   = (const float*)d_in[5];
  const float* mask_q     = (const float*)d_in[6];
  const float* mask_k     = (const float*)d_in[7];
  const float* bias_w     = (const float*)d_in[8];
  float* out = (float*)d_out;

  float* ws     = (float*)d_ws;
  float* y_part = ws;
  float* Bq     = ws + 524288;
  float* Bk     = Bq + 131072;
  float* baseq  = Bk + 131072;
  float* basek  = baseq + 16384;

  kan_precompute<<<dim3(64), dim3(256), 0, stream>>>(
      q, k, (float4*)Bq, (float4*)Bk, baseq, basek);
  kan_main<<<dim3(NOC * NIC), dim3(256), 0, stream>>>(
      coef_q, coef_k, scale_base, scale_sp, mask_q, mask_k,
      (const float4*)Bq, (const float4*)Bk, baseq, basek, y_part);
  kan_softmax<<<dim3(512), dim3(256), 0, stream>>>(y_part, bias_w, out);
}

// Round 7
// 83.698 us; speedup vs baseline: 2.7671x; 2.7671x over previous
//
#include <hip/hip_runtime.h>
#include <math.h>

// KAN attention: two spline-edge reductions (q,k branches) + bias + softmax(dim=8).
// batch=8, act_in=act_out=2048, C=8 coeffs/edge, N=4.19M edges/branch.
// HBM floor ~340 MB -> ~54 us at 6.3 TB/s achievable.
//
// R6 -> R7: the persistent 64-VGPR spill was the SCHEDULER hoisting all 48
// LDS reads of the unrolled b-loop above the FMAs (~144 VGPRs live ->
// scratch; 70-106 MB WRITE_SIZE, ~300 MB reload FETCH). Two-part fix:
// (1) sched_barrier(0) after each b-iteration pins LDS reads to their
// iteration -> live set ~60 fits the 64-reg budget the compiler insists on;
// (2) embrace that budget: 512-thread blocks, launch_bounds(512,8), 1024
// blocks = 4/CU via 36KB LDS -> 32 waves/CU (100% occupancy), barrier-free
// 8-step o-stream per wave.

#define ACT 2048
#define BATCH 8
#define IBLK 64               // i per block (= lanes of one wave)
#define NIC (ACT / IBLK)      // 32 i-chunks
#define OBLK 64               // o per block
#define NOC (ACT / OBLK)      // 32 o-chunks

__device__ __forceinline__ float dot4(const float4& a, const float4& b) {
  float r = a.x * b.x;
  r = fmaf(a.y, b.y, r);
  r = fmaf(a.z, b.z, r);
  r = fmaf(a.w, b.w, r);
  return r;
}

// ---------------------------------------------------------------------------
// Kernel 1: B-spline basis (Cox-de Boor, k=3, 12 uniform knots at -2.2+0.4j)
// and silu(x) for all (b,i) of both branches.
// Layout: B[ic][b*2+h][il] as float4 (ic=i/64, il=i%64), base[ic][b][il].
// ---------------------------------------------------------------------------
__global__ void kan_precompute(const float* __restrict__ q, const float* __restrict__ k,
                               float4* __restrict__ Bq, float4* __restrict__ Bk,
                               float* __restrict__ baseq, float* __restrict__ basek) {
  int tid = blockIdx.x * blockDim.x + threadIdx.x;
  if (tid >= ACT * BATCH) return;
  int il = tid & (IBLK - 1);
  int b = (tid >> 6) & 7;
  int ic = tid >> 9;
  int i = ic * IBLK + il;
  const float t0 = -2.2f;
  const float h = 0.4f;
  for (int br = 0; br < 2; ++br) {
    const float* xsrc = br ? k : q;
    float4* Bdst = br ? Bk : Bq;
    float* basedst = br ? basek : baseq;
    float x = xsrc[(size_t)b * ACT + i];
    float Bv[11];
#pragma unroll
    for (int j = 0; j < 11; ++j) {
      float tj = t0 + h * (float)j;
      float tj1 = t0 + h * (float)(j + 1);
      Bv[j] = (x >= tj && x < tj1) ? 1.0f : 0.0f;
    }
#pragma unroll
    for (int d = 1; d <= 3; ++d) {
      float inv = 1.0f / (h * (float)d);
#pragma unroll
      for (int j = 0; j + d < 11; ++j) {
        float tj = t0 + h * (float)j;
        float tjd1 = t0 + h * (float)(j + d + 1);
        Bv[j] = (x - tj) * inv * Bv[j] + (tjd1 - x) * inv * Bv[j + 1];
      }
    }
    Bdst[((size_t)ic * 16 + b * 2 + 0) * IBLK + il] = make_float4(Bv[0], Bv[1], Bv[2], Bv[3]);
    Bdst[((size_t)ic * 16 + b * 2 + 1) * IBLK + il] = make_float4(Bv[4], Bv[5], Bv[6], Bv[7]);
    basedst[((size_t)ic * 8 + b) * IBLK + il] = x / (1.0f + expf(-x));
  }
}

// ---------------------------------------------------------------------------
// Kernel 2: main reduction. 1024 blocks x 512 threads, 4 blocks/CU (36 KB
// LDS) x 8 waves = 32 waves/CU. Block = (ic: 64 i) x (oc: 64 o); wave w
// handles 1 o per step, 8 steps, NO barriers in the loop. Per step: 8 VMEM
// loads up front, then the b-loop reads B fragments from LDS with a
// sched_barrier(0) fence per iteration (prevents the LDS-read hoist that
// spilled R4-R6), two-stage butterfly reduce, plain store to y_part.
// ---------------------------------------------------------------------------
__global__ __launch_bounds__(512, 8) void kan_main(
    const float* __restrict__ coef_q, const float* __restrict__ coef_k,
    const float* __restrict__ scale_base, const float* __restrict__ scale_sp,
    const float* __restrict__ mask_q, const float* __restrict__ mask_k,
    const float4* __restrict__ Bq, const float4* __restrict__ Bk,
    const float* __restrict__ baseq, const float* __restrict__ basek,
    float* __restrict__ y_part) {
  __shared__ float4 BsQ[16 * IBLK];   // [(b*2+h)*64 + il]
  __shared__ float4 BsK[16 * IBLK];
  __shared__ float basQ[8 * IBLK];    // [b*64 + il]
  __shared__ float basK[8 * IBLK];

  const int t = threadIdx.x;
  const int l = t & 63;               // lane = i within chunk
  const int w = t >> 6;               // wave index (0..7)
  const int oc = blockIdx.x >> 5;
  const int ic = blockIdx.x & 31;
  const int o0 = oc * OBLK;
  const size_t ibase = (size_t)ic * IBLK + l;

  // ---- stage B/base for both branches (once per block lifetime) ----
  {
    const float4* srcq = Bq + (size_t)ic * 16 * IBLK;
    const float4* srck = Bk + (size_t)ic * 16 * IBLK;
#pragma unroll
    for (int r = 0; r < 2; ++r) {
      BsQ[r * 512 + t] = srcq[r * 512 + t];
      BsK[r * 512 + t] = srck[r * 512 + t];
    }
    if (t < 128) {
      reinterpret_cast<float4*>(basQ)[t] =
          reinterpret_cast<const float4*>(baseq + (size_t)ic * 8 * IBLK)[t];
    } else if (t < 256) {
      reinterpret_cast<float4*>(basK)[t - 128] =
          reinterpret_cast<const float4*>(basek + (size_t)ic * 8 * IBLK)[t - 128];
    }
  }
  __syncthreads();

#pragma unroll 1
  for (int s = 0; s < 8; ++s) {
    const int oa = o0 + s * 8 + w;
    const size_t e = (size_t)oa * ACT + ibase;

    // 2 x dwordx4 per branch (lane-stride 32 B, dense lines) + 4 scalars.
    const float4* cpq = reinterpret_cast<const float4*>(coef_q + e * 8);
    const float4* cpk = reinterpret_cast<const float4*>(coef_k + e * 8);
    float4 cq0 = cpq[0], cq1 = cpq[1];
    float4 ck0 = cpk[0], ck1 = cpk[1];
    float mq = mask_q[e], mk = mask_k[e];
    float sb = scale_base[e], ss = scale_sp[e];

    float vbq = mq * sb, vsq = mq * ss, vbk = mk * sb, vsk = mk * ss;

    float acc[BATCH];
#pragma unroll
    for (int b = 0; b < BATCH; ++b) {
      const float4 Bq0 = BsQ[(b * 2 + 0) * IBLK + l];
      const float4 Bq1 = BsQ[(b * 2 + 1) * IBLK + l];
      float dq = dot4(Bq0, cq0) + dot4(Bq1, cq1);
      const float4 Bk0 = BsK[(b * 2 + 0) * IBLK + l];
      const float4 Bk1 = BsK[(b * 2 + 1) * IBLK + l];
      float dk = dot4(Bk0, ck0) + dot4(Bk1, ck1);
      const float bsq = basQ[b * IBLK + l];
      const float bsk = basK[b * IBLK + l];
      float a = vsq * dq;
      a = fmaf(vsk, dk, a);
      a = fmaf(vbq, bsq, a);
      a = fmaf(vbk, bsk, a);
      acc[b] = a;
      // Pin this iteration's LDS reads + FMAs: nothing crosses. Prevents the
      // scheduler from hoisting all 8 iterations' ds_reads (the R4-R6 spill).
      __builtin_amdgcn_sched_barrier(0);
    }

    // Stage 1: 3-level butterfly over low lane bits -> every lane holds its
    // octet's sum for all 8 b.
#pragma unroll
    for (int b = 0; b < BATCH; ++b) {
#pragma unroll
      for (int off = 1; off < 8; off <<= 1) acc[b] += __shfl_xor(acc[b], off);
    }
    // Stage 2: select b = l&7 (compile-time-indexed cndmask chain), then
    // 3 more levels across octets -> total sum for b=l&7 in every lane.
    float v = acc[0];
#pragma unroll
    for (int b = 1; b < BATCH; ++b) v = ((l & 7) == b) ? acc[b] : v;
#pragma unroll
    for (int off = 8; off < 64; off <<= 1) v += __shfl_xor(v, off);

    if (l < 8) y_part[(size_t)oa * (NIC * 8) + ic * 8 + l] = v;
  }
}

// ---------------------------------------------------------------------------
// Kernel 3: sum 32 i-chunk partials per (o,b), add bias, softmax over groups
// of 8 outputs. One wave per output row (b,grp); 4 rows per 256-thread block.
// Lane l: op = l>>3 (8 o's), sub = l&7 (partial-chunk slice).
// ---------------------------------------------------------------------------
__global__ void kan_softmax(const float* __restrict__ y_part,
                            const float* __restrict__ bias,
                            float* __restrict__ out) {
  const int t = threadIdx.x;
  const int wid = blockIdx.x * 4 + (t >> 6);   // row id, 0..2047
  const int b = wid >> 8;
  const int grp = wid & 255;
  const int l = t & 63;
  const int op = l >> 3;                       // o within group
  const int sub = l & 7;
  const int o = grp * 8 + op;

  float p = 0.0f;
#pragma unroll
  for (int j = 0; j < 4; ++j) {
    int icc = sub + 8 * j;
    p += y_part[(size_t)o * (NIC * 8) + icc * 8 + b];
  }
  // sum the 8 sub-partials within each o-group (lanes 8*op .. 8*op+7)
#pragma unroll
  for (int off = 1; off < 8; off <<= 1) p += __shfl_xor(p, off);
  float v = p + bias[o];
  // softmax across the 8 o-groups (xor offs 8,16,32 span the groups)
  float m = v;
#pragma unroll
  for (int off = 8; off < 64; off <<= 1) m = fmaxf(m, __shfl_xor(m, off));
  float e = expf(v - m);
  float ssum = e;
#pragma unroll
  for (int off = 8; off < 64; off <<= 1) ssum += __shfl_xor(ssum, off);
  if (sub == 0) out[(size_t)b * ACT + o] = e / ssum;
}

// ---------------------------------------------------------------------------
// Workspace layout (floats):
//   y_part @ 0      : 524288  ([o][ic][b], fully rewritten each call)
//   Bq     @ 524288 : 131072  ([ic][b*2+h][il] float4)
//   Bk     @ 655360 : 131072
//   baseq  @ 786432 : 16384   ([ic][b][il])
//   basek  @ 802816 : 16384
// total 819200 floats = 3.125 MiB. No init needed (every slot written).
// ---------------------------------------------------------------------------
extern "C" void kernel_launch(void* const* d_in, const int* in_sizes, int n_in,
                              void* d_out, int out_size, void* d_ws, size_t ws_size,
                              hipStream_t stream) {
  const float* q          = (const float*)d_in[0];
  const float* k          = (const float*)d_in[1];
  const float* coef_q     = (const float*)d_in[2];
  const float* coef_k     = (const float*)d_in[3];
  const float* scale_base = (const float*)d_in[4];
  const float* scale_sp   = (const float*)d_in[5];
  const float* mask_q     = (const float*)d_in[6];
  const float* mask_k     = (const float*)d_in[7];
  const float* bias_w     = (const float*)d_in[8];
  float* out = (float*)d_out;

  float* ws     = (float*)d_ws;
  float* y_part = ws;
  float* Bq     = ws + 524288;
  float* Bk     = Bq + 131072;
  float* baseq  = Bk + 131072;
  float* basek  = baseq + 16384;

  kan_precompute<<<dim3(64), dim3(256), 0, stream>>>(
      q, k, (float4*)Bq, (float4*)Bk, baseq, basek);
  kan_main<<<dim3(NOC * NIC), dim3(512), 0, stream>>>(
      coef_q, coef_k, scale_base, scale_sp, mask_q, mask_k,
      (const float4*)Bq, (const float4*)Bk, baseq, basek, y_part);
  kan_softmax<<<dim3(512), dim3(256), 0, stream>>>(y_part, bias_w, out);
}